// Round 9
// baseline (1175.620 us; speedup 1.0000x reference)
//
#include <hip/hip_runtime.h>

typedef short bf16x8 __attribute__((ext_vector_type(8)));
typedef float f32x4  __attribute__((ext_vector_type(4)));

#define T_TOK 16384
#define HD 768
#define ID 3072
#define NE 8
#define NTM64 520        // max 64-row tiles: 32768/64 + 8 partials

__device__ __forceinline__ unsigned short f2bf(float f) {
    unsigned int u = __float_as_uint(f);
    unsigned int r = (u + 0x7FFFu + ((u >> 16) & 1u)) >> 16;   // RNE
    return (unsigned short)r;
}

__device__ __forceinline__ void gload16(const void* g, void* l) {
    __builtin_amdgcn_global_load_lds(
        (const __attribute__((address_space(1))) void*)g,
        (__attribute__((address_space(3))) void*)l, 16, 0, 0);
}

__device__ __forceinline__ void vmw(int n) {   // n is compile-time post-unroll
    if (n == 0)      asm volatile("s_waitcnt vmcnt(0)" ::: "memory");
    else if (n == 2) asm volatile("s_waitcnt vmcnt(2)" ::: "memory");
    else if (n == 3) asm volatile("s_waitcnt vmcnt(3)" ::: "memory");
    else             asm volatile("s_waitcnt vmcnt(4)" ::: "memory");
}

__device__ __forceinline__ float gelu_f(float x) {
    float z = fabsf(x) * 0.70710678118f;
    float t = 1.0f / fmaf(0.3275911f, z, 1.0f);
    float p = t * fmaf(t, fmaf(t, fmaf(t, fmaf(t, 1.061405429f, -1.453152027f),
                                       1.421413741f), -0.284496736f), 0.254829592f);
    float e = 1.0f - p * __expf(-z * z);
    float erfv = (x >= 0.f) ? e : -e;
    return 0.5f * x * (1.0f + erfv);
}

__device__ __forceinline__ int xcd_swz(int bid, int nwg) {
    int q = nwg >> 3, rr = nwg & 7;
    int xcd = bid & 7, seq = bid >> 3;
    return (xcd < rr ? xcd * (q + 1) : rr * (q + 1) + (xcd - rr) * q) + seq;
}

// ---------------- x f32 -> bf16 ----------------
__global__ __launch_bounds__(256) void k_cvt_x(const float* __restrict__ x,
                                               unsigned short* __restrict__ xb) {
    int i = blockIdx.x * 256 + threadIdx.x;
    float4 v = ((const float4*)x)[i];
    ushort4 o;
    o.x = f2bf(v.x); o.y = f2bf(v.y); o.z = f2bf(v.z); o.w = f2bf(v.w);
    ((ushort4*)xb)[i] = o;
}

// ---------------- transpose + cvt: in [E][R][C] f32 -> out [E][C][R] bf16 ----
__global__ __launch_bounds__(256) void k_tp(const float* __restrict__ in,
                                            unsigned short* __restrict__ out,
                                            int R, int C) {
    __shared__ float t[64][65];
    const float* ine = in + (size_t)blockIdx.z * R * C;
    unsigned short* oute = out + (size_t)blockIdx.z * R * C;
    int c0 = blockIdx.x * 64, r0 = blockIdx.y * 64;
    int lc = threadIdx.x & 63, lr4 = threadIdx.x >> 6;
#pragma unroll
    for (int i = 0; i < 16; i++) {
        int r = i * 4 + lr4;
        t[r][lc] = ine[(size_t)(r0 + r) * C + c0 + lc];
    }
    __syncthreads();
#pragma unroll
    for (int i = 0; i < 16; i++) {
        int r = i * 4 + lr4;
        oute[(size_t)(c0 + r) * R + r0 + lc] = f2bf(t[lc][r]);
    }
}

// ---------------- router ----------------
__global__ __launch_bounds__(256) void k_router(const float* __restrict__ x,
                                                const float* __restrict__ rw,
                                                int* __restrict__ topE,
                                                float* __restrict__ topW) {
    __shared__ float lrw[NE * HD];
    for (int i = threadIdx.x; i < NE * HD; i += 256) lrw[i] = rw[i];
    __syncthreads();
    int lane = threadIdx.x & 63;
    int t = blockIdx.x * 4 + (threadIdx.x >> 6);
    const float* xr = x + (size_t)t * HD;
    float acc[NE] = {0, 0, 0, 0, 0, 0, 0, 0};
    for (int h = lane; h < HD; h += 64) {
        float xv = xr[h];
#pragma unroll
        for (int e = 0; e < NE; e++) acc[e] = fmaf(xv, lrw[e * HD + h], acc[e]);
    }
#pragma unroll
    for (int e = 0; e < NE; e++) {
        float v = acc[e];
#pragma unroll
        for (int o = 32; o > 0; o >>= 1) v += __shfl_xor(v, o, 64);
        acc[e] = v;
    }
    if (lane == 0) {
        int e1 = 0; float l1 = acc[0];
#pragma unroll
        for (int e = 1; e < NE; e++) if (acc[e] > l1) { l1 = acc[e]; e1 = e; }
        int e2 = -1; float l2 = -1e30f;
#pragma unroll
        for (int e = 0; e < NE; e++) if (e != e1 && acc[e] > l2) { l2 = acc[e]; e2 = e; }
        float ex = expf(l2 - l1);
        float w1 = 1.0f / (1.0f + ex);
        topE[2 * t] = e1; topE[2 * t + 1] = e2;
        topW[2 * t] = w1; topW[2 * t + 1] = ex * w1;
    }
}

// ---------------- scatter ----------------
__global__ __launch_bounds__(256) void k_scatter(const int* __restrict__ topE,
                                                 const float* __restrict__ topW,
                                                 int* __restrict__ counts,
                                                 int* __restrict__ tokL,
                                                 float* __restrict__ gateL) {
    __shared__ int lc[NE], lbase[NE];
    if (threadIdx.x < NE) lc[threadIdx.x] = 0;
    __syncthreads();
    int t = blockIdx.x * 256 + threadIdx.x;
    int e1 = topE[2 * t], e2 = topE[2 * t + 1];
    int p1 = atomicAdd(&lc[e1], 1);
    int p2 = atomicAdd(&lc[e2], 1);
    __syncthreads();
    if (threadIdx.x < NE) lbase[threadIdx.x] = atomicAdd(&counts[threadIdx.x], lc[threadIdx.x]);
    __syncthreads();
    int q1 = lbase[e1] + p1, q2 = lbase[e2] + p2;
    tokL[e1 * T_TOK + q1] = t;  gateL[e1 * T_TOK + q1] = topW[2 * t];
    tokL[e2 * T_TOK + q2] = t;  gateL[e2 * T_TOK + q2] = topW[2 * t + 1];
}

// ---------------- tile descriptor: 64-row tiles ----------------
__global__ void k_desc(const int* __restrict__ counts, int* __restrict__ tileE,
                       int* __restrict__ tileM0) {
    if (threadIdx.x == 0 && blockIdx.x == 0) {
        int tl = 0;
        for (int e = 0; e < NE; e++) {
            int c = counts[e];
            int nt = (c + 63) >> 6;
            for (int t = 0; t < nt; t++) { tileE[tl] = e; tileM0[tl] = t << 6; tl++; }
        }
        for (; tl < NTM64; tl++) { tileE[tl] = -1; tileM0[tl] = 0; }
    }
}

// ================= FUSED MoE block: 64 tokens x 1 expert =================
// 8 waves (4M x 2N). X-frags in registers (24 bf16x8/lane, loaded once).
// Per I-chunk ci (24 chunks of 128):
//  UP (12 steps, BK=64): U-tile 16KB via 3-slot ring, depth-2 counted vmcnt;
//    D(ci,0)/D(ci,1) pre-staged as 1 chunk/wave/step singles (t=0..5 / 6..11).
//  h[64x128] -> gelu -> LDS (frag-matched 1KB chunks).
//  DOWN (4 steps, BK=32): 48KB tiles in 2 slots; s1/s2 stage D2/D3 + U(ci+1,0/1).
// All vmcnt waits are per-wave BEFORE the shared barrier (cross-wave safe).
// LDS map: h [0,16K) | U 16K+u*16K (u<3) | D 64K+d*48K (d<2) = 160KiB exact.
__global__ __launch_bounds__(512, 2) void k_fused(
    const unsigned short* __restrict__ xb,
    const unsigned short* __restrict__ upt,     // [E][I][H]
    const unsigned short* __restrict__ dnt,     // [E][H][I]
    const int* __restrict__ counts,
    const int* __restrict__ tokL,
    const float* __restrict__ gateL,
    const int* __restrict__ tileE,
    const int* __restrict__ tileM0,
    float* __restrict__ out) {
    __shared__ __align__(16) char lds[163840];

    int L = xcd_swz(blockIdx.x, gridDim.x);
    int e = tileE[L];
    if (e < 0) return;
    int m0 = tileM0[L];
    int nrow = min(64, counts[e] - m0);
    const int* tok = tokL + e * T_TOK + m0;
    const float* gat = gateL + e * T_TOK + m0;

    const int tid = threadIdx.x, lane = tid & 63, wid = tid >> 6;
    const int wm = wid >> 1, wn = wid & 1;
    const int g = lane >> 4, r = lane & 15;
    const int foff = g * 256 + r * 16;

    const char* upe = (const char*)(upt + (size_t)e * ID * HD);
    const char* dne = (const char*)(dnt + (size_t)e * ID * HD);

    // ---- X-frags in registers: wave wm's 16 token rows, 24 k-slices
    bf16x8 xf[24];
    {
        int row = wm * 16 + r;
        int tk = tok[row < nrow ? row : 0];
        const char* xs = (const char*)xb + (size_t)tk * 1536 + g * 16;
#pragma unroll
        for (int s = 0; s < 24; s++) xf[s] = *(const bf16x8*)(xs + s * 64);
    }
    // ---- epilogue tokens/gates
    int t4[4]; float g4[4];
#pragma unroll
    for (int j = 0; j < 4; j++) {
        int rl = wm * 16 + g * 4 + j;
        bool v = rl < nrow;
        t4[j] = v ? tok[rl] : -1;
        g4[j] = v ? gat[rl] : 0.f;
    }

    // ---- stage bases
    const char* uB = upe + (size_t)(wid * 16 + r) * 1536 + g * 16;   // +ci*196608 + t*128 + kh*64
    const char* dB0 = dne + (size_t)(wid * 96 + r) * 6144 + g * 16;  // +q*98304 + ci*256 + ks*64

    auto stgU = [&](int ci_, int t_, int slot_) {
        const char* s0 = uB + (size_t)ci_ * 196608 + t_ * 128;
        char* d = lds + 16384 + slot_ * 16384 + wid * 2048;
        gload16(s0, d);
        gload16(s0 + 64, d + 1024);
    };

    f32x4 accD[24];
#pragma unroll
    for (int n = 0; n < 24; n++) accD[n] = (f32x4){0.f, 0.f, 0.f, 0.f};

    auto downStep = [&](const char* dsl, int s) {
        bf16x8 af = *(const bf16x8*)(lds + (wm * 4 + s) * 1024 + foff);
        __builtin_amdgcn_s_setprio(1);
#pragma unroll
        for (int grp = 0; grp < 4; grp++) {
            bf16x8 bb[6];
#pragma unroll
            for (int q = 0; q < 6; q++)
                bb[q] = *(const bf16x8*)(dsl + (wn * 24 + grp * 6 + q) * 1024 + foff);
#pragma unroll
            for (int q = 0; q < 6; q++)
                accD[grp * 6 + q] = __builtin_amdgcn_mfma_f32_16x16x32_bf16(af, bb[q], accD[grp * 6 + q], 0, 0, 0);
        }
        __builtin_amdgcn_s_setprio(0);
    };

    // ---- prologue: U(0,0)->slot0, U(0,1)->slot1
    stgU(0, 0, 0);
    stgU(0, 1, 1);
    asm volatile("s_waitcnt vmcnt(0)" ::: "memory");
    __builtin_amdgcn_s_barrier();
    asm volatile("" ::: "memory");

    for (int ci = 0; ci < 24; ci++) {
        // ================= UP phase: 12 steps =================
        f32x4 ah[4];
#pragma unroll
        for (int n = 0; n < 4; n++) ah[n] = (f32x4){0.f, 0.f, 0.f, 0.f};

#pragma unroll
        for (int t = 0; t < 12; t++) {
            if (t < 10) stgU(ci, t + 2, (t + 2) % 3);
            {   // D-single: D(ci,0) chunks at t=0..5, D(ci,1) at t=6..11
                int q = (t < 6) ? t : t - 6;
                int ks = (t < 6) ? 0 : 1;
                gload16(dB0 + (size_t)q * 98304 + ci * 256 + ks * 64,
                        lds + 65536 + ks * 49152 + (wid * 6 + q) * 1024);
            }
            const char* ub = lds + 16384 + (t % 3) * 16384;
            __builtin_amdgcn_s_setprio(1);
#pragma unroll
            for (int nf = 0; nf < 4; nf++)
#pragma unroll
                for (int kh = 0; kh < 2; kh++) {
                    bf16x8 bb = *(const bf16x8*)(ub + ((wn * 4 + nf) * 2 + kh) * 1024 + foff);
                    ah[nf] = __builtin_amdgcn_mfma_f32_16x16x32_bf16(xf[t * 2 + kh], bb, ah[nf], 0, 0, 0);
                }
            __builtin_amdgcn_s_setprio(0);
            // exact queue algebra: need U(t+1) landed before next step
            vmw((t == 0) ? 3 : (t <= 9) ? 4 : (t == 10) ? 2 : 0);
            __builtin_amdgcn_s_barrier();
            asm volatile("" ::: "memory");
        }

        // ================= h = gelu(ah) -> LDS =================
#pragma unroll
        for (int nf = 0; nf < 4; nf++) {
            int i = wn * 64 + nf * 16 + r;
            int kk = i & 31, ks = i >> 5;
#pragma unroll
            for (int j = 0; j < 4; j++) {
                int row = g * 4 + j;
                *(unsigned short*)(lds + (wm * 4 + ks) * 1024 + (kk >> 3) * 256 + row * 16 + (kk & 7) * 2)
                    = f2bf(gelu_f(ah[nf][j]));
            }
        }
        asm volatile("s_waitcnt lgkmcnt(0)" ::: "memory");
        __builtin_amdgcn_s_barrier();
        asm volatile("" ::: "memory");

        // ================= DOWN phase: 4 steps =================
        int cin = (ci + 1 < 24) ? ci + 1 : 23;
        // s0: read D0 (slot0)
        downStep(lds + 65536, 0);
        __builtin_amdgcn_s_barrier();
        asm volatile("" ::: "memory");
        // s1: stage D2->slot0, U(ci+1,0)->slot0(U); read D1 (slot1)
#pragma unroll
        for (int q = 0; q < 6; q++)
            gload16(dB0 + (size_t)q * 98304 + ci * 256 + 2 * 64,
                    lds + 65536 + (wid * 6 + q) * 1024);
        stgU(cin, 0, 0);
        downStep(lds + 65536 + 49152, 1);
        vmw(2);                                    // D2 landed; U0 floats
        __builtin_amdgcn_s_barrier();
        asm volatile("" ::: "memory");
        // s2: stage D3->slot1, U(ci+1,1)->slot1(U); read D2 (slot0)
#pragma unroll
        for (int q = 0; q < 6; q++)
            gload16(dB0 + (size_t)q * 98304 + ci * 256 + 3 * 64,
                    lds + 65536 + 49152 + (wid * 6 + q) * 1024);
        stgU(cin, 1, 1);
        downStep(lds + 65536, 2);
        vmw(2);                                    // D3 landed; U1 floats
        __builtin_amdgcn_s_barrier();
        asm volatile("" ::: "memory");
        // s3: read D3 (slot1)
        downStep(lds + 65536 + 49152, 3);
        vmw(0);                                    // U0,U1 landed
        __builtin_amdgcn_s_barrier();
        asm volatile("" ::: "memory");
    }

    // ================= epilogue: gate + atomicAdd =================
#pragma unroll
    for (int nf = 0; nf < 24; nf++) {
        int col = wn * 384 + nf * 16 + r;
#pragma unroll
        for (int j = 0; j < 4; j++) {
            if (t4[j] >= 0)
                atomicAdd(out + (size_t)t4[j] * HD + col, g4[j] * accD[nf][j]);
        }
    }
}

extern "C" void kernel_launch(void* const* d_in, const int* in_sizes, int n_in,
                              void* d_out, int out_size, void* d_ws, size_t ws_size,
                              hipStream_t stream) {
    const float* x  = (const float*)d_in[0];
    const float* rw = (const float*)d_in[1];
    const float* uw = (const float*)d_in[2];
    const float* dw = (const float*)d_in[3];
    float* out = (float*)d_out;

    size_t off = 0;
    char* base = (char*)d_ws;
    auto alloc = [&](size_t bytes) -> char* {
        char* p = base + off;
        off += (bytes + 1023) & ~(size_t)1023;
        return p;
    };
    unsigned short* xb   = (unsigned short*)alloc((size_t)T_TOK * HD * 2);
    unsigned short* upt  = (unsigned short*)alloc((size_t)NE * ID * HD * 2);
    unsigned short* dnt  = (unsigned short*)alloc((size_t)NE * HD * ID * 2);
    int*   topE   = (int*)alloc((size_t)T_TOK * 2 * 4);
    float* topW   = (float*)alloc((size_t)T_TOK * 2 * 4);
    int*   counts = (int*)alloc(256);
    int*   tileE  = (int*)alloc(NTM64 * 4);
    int*   tileM0 = (int*)alloc(NTM64 * 4);
    int*   tokL   = (int*)alloc((size_t)NE * T_TOK * 4);
    float* gateL  = (float*)alloc((size_t)NE * T_TOK * 4);

    hipMemsetAsync(d_out, 0, (size_t)T_TOK * HD * 4, stream);
    hipMemsetAsync(counts, 0, 256, stream);

    k_cvt_x<<<(T_TOK * HD) / (256 * 4), 256, 0, stream>>>(x, xb);
    k_tp<<<dim3(ID / 64, HD / 64, NE), 256, 0, stream>>>(uw, upt, HD, ID);   // -> [i][h]
    k_tp<<<dim3(HD / 64, ID / 64, NE), 256, 0, stream>>>(dw, dnt, ID, HD);   // -> [h][i]
    k_router<<<T_TOK / 4, 256, 0, stream>>>(x, rw, topE, topW);
    k_scatter<<<T_TOK / 256, 256, 0, stream>>>(topE, topW, counts, tokL, gateL);
    k_desc<<<1, 64, 0, stream>>>(counts, tileE, tileM0);
    k_fused<<<NTM64, 512, 0, stream>>>(xb, upt, dnt, counts, tokL, gateL, tileE, tileM0, out);
}

// Round 10
// 754.880 us; speedup vs baseline: 1.5574x; 1.5574x over previous
//
#include <hip/hip_runtime.h>

typedef short bf16x8 __attribute__((ext_vector_type(8)));
typedef float f32x4  __attribute__((ext_vector_type(4)));

#define T_TOK 16384
#define HD 768
#define ID 3072
#define NE 8
#define NT1MAX 136       // max 256-row tiles: 32768/256 + 8 partials

__device__ __forceinline__ unsigned short f2bf(float f) {
    unsigned int u = __float_as_uint(f);
    unsigned int r = (u + 0x7FFFu + ((u >> 16) & 1u)) >> 16;   // RNE
    return (unsigned short)r;
}

__device__ __forceinline__ void gload16(const void* g, void* l) {
    __builtin_amdgcn_global_load_lds(
        (const __attribute__((address_space(1))) void*)g,
        (__attribute__((address_space(3))) void*)l, 16, 0, 0);
}

__device__ __forceinline__ float gelu_f(float x) {
    // exact-GELU via A&S 7.1.26 erf approx (|err| <= 1.5e-7, invisible at bf16)
    float z = fabsf(x) * 0.70710678118f;
    float t = 1.0f / fmaf(0.3275911f, z, 1.0f);
    float p = t * fmaf(t, fmaf(t, fmaf(t, fmaf(t, 1.061405429f, -1.453152027f),
                                       1.421413741f), -0.284496736f), 0.254829592f);
    float e = 1.0f - p * __expf(-z * z);
    float erfv = (x >= 0.f) ? e : -e;
    return 0.5f * x * (1.0f + erfv);
}

__device__ __forceinline__ int xcd_swz(int bid, int nwg) {
    // bijective XCD-chunked remap (m204)
    int q = nwg >> 3, rr = nwg & 7;
    int xcd = bid & 7, seq = bid >> 3;
    return (xcd < rr ? xcd * (q + 1) : rr * (q + 1) + (xcd - rr) * q) + seq;
}

// ---------------- transpose + cvt: in [E][R][C] f32 -> out [E][C][R] bf16 ----
__global__ __launch_bounds__(256) void k_tp(const float* __restrict__ in,
                                            unsigned short* __restrict__ out,
                                            int R, int C) {
    __shared__ float t[64][65];
    const float* ine = in + (size_t)blockIdx.z * R * C;
    unsigned short* oute = out + (size_t)blockIdx.z * R * C;
    int c0 = blockIdx.x * 64, r0 = blockIdx.y * 64;
    int lc = threadIdx.x & 63, lr4 = threadIdx.x >> 6;
#pragma unroll
    for (int i = 0; i < 16; i++) {
        int r = i * 4 + lr4;
        t[r][lc] = ine[(size_t)(r0 + r) * C + c0 + lc];
    }
    __syncthreads();
#pragma unroll
    for (int i = 0; i < 16; i++) {
        int r = i * 4 + lr4;
        oute[(size_t)(c0 + r) * R + r0 + lc] = f2bf(t[lc][r]);
    }
}

// ---------------- router + x->bf16 cvt (fused) ----------------
__global__ __launch_bounds__(256) void k_router(const float* __restrict__ x,
                                                const float* __restrict__ rw,
                                                unsigned short* __restrict__ xb,
                                                int* __restrict__ topE,
                                                float* __restrict__ topW) {
    __shared__ float lrw[NE * HD];
    for (int i = threadIdx.x; i < NE * HD; i += 256) lrw[i] = rw[i];
    // fused cvt: this block's 4 token rows (3072 floats = 768 float4)
    {
        const float4* xs4 = (const float4*)(x + (size_t)blockIdx.x * 4 * HD);
        ushort4* xb4 = (ushort4*)(xb + (size_t)blockIdx.x * 4 * HD);
#pragma unroll
        for (int i = 0; i < 3; i++) {
            float4 v = xs4[threadIdx.x + i * 256];
            ushort4 o;
            o.x = f2bf(v.x); o.y = f2bf(v.y); o.z = f2bf(v.z); o.w = f2bf(v.w);
            xb4[threadIdx.x + i * 256] = o;
        }
    }
    __syncthreads();
    int lane = threadIdx.x & 63;
    int t = blockIdx.x * 4 + (threadIdx.x >> 6);
    const float* xr = x + (size_t)t * HD;
    float acc[NE] = {0, 0, 0, 0, 0, 0, 0, 0};
    for (int h = lane; h < HD; h += 64) {
        float xv = xr[h];
#pragma unroll
        for (int e = 0; e < NE; e++) acc[e] = fmaf(xv, lrw[e * HD + h], acc[e]);
    }
#pragma unroll
    for (int e = 0; e < NE; e++) {
        float v = acc[e];
#pragma unroll
        for (int o = 32; o > 0; o >>= 1) v += __shfl_xor(v, o, 64);
        acc[e] = v;
    }
    if (lane == 0) {
        int e1 = 0; float l1 = acc[0];
#pragma unroll
        for (int e = 1; e < NE; e++) if (acc[e] > l1) { l1 = acc[e]; e1 = e; }
        int e2 = -1; float l2 = -1e30f;
#pragma unroll
        for (int e = 0; e < NE; e++) if (e != e1 && acc[e] > l2) { l2 = acc[e]; e2 = e; }
        float ex = expf(l2 - l1);
        float w1 = 1.0f / (1.0f + ex);
        topE[2 * t] = e1; topE[2 * t + 1] = e2;
        topW[2 * t] = w1; topW[2 * t + 1] = ex * w1;
    }
}

// ---------------- scatter into per-expert lists ----------------
__global__ __launch_bounds__(256) void k_scatter(const int* __restrict__ topE,
                                                 const float* __restrict__ topW,
                                                 int* __restrict__ counts,
                                                 int* __restrict__ tokL,
                                                 float* __restrict__ gateL) {
    __shared__ int lc[NE], lbase[NE];
    if (threadIdx.x < NE) lc[threadIdx.x] = 0;
    __syncthreads();
    int t = blockIdx.x * 256 + threadIdx.x;
    int e1 = topE[2 * t], e2 = topE[2 * t + 1];
    int p1 = atomicAdd(&lc[e1], 1);
    int p2 = atomicAdd(&lc[e2], 1);
    __syncthreads();
    if (threadIdx.x < NE) lbase[threadIdx.x] = atomicAdd(&counts[threadIdx.x], lc[threadIdx.x]);
    __syncthreads();
    int q1 = lbase[e1] + p1, q2 = lbase[e2] + p2;
    tokL[e1 * T_TOK + q1] = t;  gateL[e1 * T_TOK + q1] = topW[2 * t];
    tokL[e2 * T_TOK + q2] = t;  gateL[e2 * T_TOK + q2] = topW[2 * t + 1];
}

// ---------------- tile descriptor build: 256-row tiles ----------------
__global__ void k_desc(const int* __restrict__ counts, int* __restrict__ tileE,
                       int* __restrict__ tileM0) {
    if (threadIdx.x == 0 && blockIdx.x == 0) {
        int tl = 0;
        for (int e = 0; e < NE; e++) {
            int c = counts[e];
            int nt = (c + 255) >> 8;
            for (int t = 0; t < nt; t++) { tileE[tl] = e; tileM0[tl] = t << 8; tl++; }
        }
        for (; tl < NT1MAX; tl++) { tileE[tl] = -1; tileM0[tl] = 0; }
    }
}

// ============ grouped GEMM1 (I-segment): h_seg = gelu( Xg @ up_seg^T ) ============
// 256x256 tile, BK=32, 5-slot LDS ring (160KB exact), depth-3 prefetch, vmcnt(12).
// Per-wave vmcnt BEFORE the shared barrier (r7 race discipline). Tail dummies land in
// retired slot (k+4)%5 = (k-1)%5, never re-read. LDS slot: A/B in [chunk16row][g4][r16]x16B
// -> gload dst wave-uniform (G21), all ds_read_b128 contiguous-1KB (conflict-free).
__global__ __launch_bounds__(512, 1) void k_gemm1(
    const unsigned short* __restrict__ xb,
    const unsigned short* __restrict__ upt,     // [E][I][H] bf16
    const int* __restrict__ tokL,
    const int* __restrict__ counts,
    const int* __restrict__ tileE,
    const int* __restrict__ tileM0,
    unsigned short* __restrict__ h,             // [NT1MAX*256][ldh]
    int seg, int ntn, int ldh) {
    __shared__ __align__(16) char lds[5][32768];
    constexpr int NK = HD / 32;                 // 24
    int L = xcd_swz(blockIdx.x, gridDim.x);
    int mt = L / ntn, ntl = L - mt * ntn;
    int e = tileE[mt];
    if (e < 0) return;
    int m0 = tileM0[mt];
    int nrow = min(256, counts[e] - m0);
    const int* tok = tokL + e * T_TOK + m0;
    int n0 = (seg * ntn + ntl) * 256;           // global I-row of B panel

    const int tid = threadIdx.x, lane = tid & 63, wid = tid >> 6;
    const int wm = wid >> 2, wn = wid & 3;
    const int g = lane >> 4, r = lane & 15;

    int ar0 = wid * 16 + r;
    int ar1 = 128 + wid * 16 + r;
    const char* a0 = (const char*)(xb + (size_t)tok[ar0 < nrow ? ar0 : 0] * HD) + g * 16;
    const char* a1 = (const char*)(xb + (size_t)tok[ar1 < nrow ? ar1 : 0] * HD) + g * 16;
    const char* bsl = (const char*)(upt + (size_t)e * ID * HD);
    const char* b0 = bsl + (size_t)(n0 + wid * 16 + r) * (HD * 2) + g * 16;
    const char* b1 = bsl + (size_t)(n0 + 128 + wid * 16 + r) * (HD * 2) + g * 16;
    const int dst = wid * 1024;                 // wave-uniform; HW adds lane*16

    auto issue = [&](int step, int slot) {
        char* base = &lds[slot][0];
        int kb = step * 64;
        gload16(a0 + kb, base + dst);
        gload16(a1 + kb, base + 8192 + dst);
        gload16(b0 + kb, base + 16384 + dst);
        gload16(b1 + kb, base + 24576 + dst);
    };

    f32x4 acc[8][4];
#pragma unroll
    for (int m = 0; m < 8; m++)
#pragma unroll
        for (int n = 0; n < 4; n++) acc[m][n] = (f32x4){0.f, 0.f, 0.f, 0.f};

    issue(0, 0); issue(1, 1); issue(2, 2); issue(3, 3);
    asm volatile("s_waitcnt vmcnt(12)" ::: "memory");
    __builtin_amdgcn_s_barrier();
    asm volatile("" ::: "memory");

    const int aoff = wm * 8192 + g * 256 + r * 16;
    const int boff = 16384 + wn * 4096 + g * 256 + r * 16;

    for (int k = 0; k < NK; k++) {
        char* base = &lds[k % 5][0];
        bf16x8 a[4], b[4];
#pragma unroll
        for (int n = 0; n < 4; n++) b[n] = *(const bf16x8*)(base + boff + n * 1024);
#pragma unroll
        for (int m = 0; m < 4; m++) a[m] = *(const bf16x8*)(base + aoff + m * 1024);
        issue(min(k + 4, NK - 1), (k + 4) % 5);
        __builtin_amdgcn_s_setprio(1);
#pragma unroll
        for (int m = 0; m < 4; m++)
#pragma unroll
            for (int n = 0; n < 4; n++)
                acc[m][n] = __builtin_amdgcn_mfma_f32_16x16x32_bf16(a[m], b[n], acc[m][n], 0, 0, 0);
        __builtin_amdgcn_s_setprio(0);
#pragma unroll
        for (int m = 0; m < 4; m++) a[m] = *(const bf16x8*)(base + aoff + (4 + m) * 1024);
        __builtin_amdgcn_s_setprio(1);
#pragma unroll
        for (int m = 0; m < 4; m++)
#pragma unroll
            for (int n = 0; n < 4; n++)
                acc[4 + m][n] = __builtin_amdgcn_mfma_f32_16x16x32_bf16(a[m], b[n], acc[4 + m][n], 0, 0, 0);
        __builtin_amdgcn_s_setprio(0);
        asm volatile("s_waitcnt vmcnt(12)" ::: "memory");   // per-wave: tile k+1 landed
        __builtin_amdgcn_s_barrier();
        asm volatile("" ::: "memory");
    }
    asm volatile("s_waitcnt vmcnt(0)" ::: "memory");

#pragma unroll
    for (int m = 0; m < 8; m++)
#pragma unroll
        for (int j = 0; j < 4; j++) {
            int rl = wm * 128 + m * 16 + g * 4 + j;
            if (rl < nrow) {
                unsigned short* hr = h + (size_t)(mt * 256 + rl) * ldh + ntl * 256 + wn * 64 + r;
#pragma unroll
                for (int n = 0; n < 4; n++) hr[n * 16] = f2bf(gelu_f(acc[m][n][j]));
            }
        }
}

// ============ grouped GEMM2 (I-segment): out[tok] += gate * ( h_seg @ down_seg^T ) ====
__global__ __launch_bounds__(512, 1) void k_gemm2(
    const unsigned short* __restrict__ h,       // [NT1MAX*256][ldh]
    const unsigned short* __restrict__ dnt,     // [E][H][I] bf16
    const int* __restrict__ tokL,
    const float* __restrict__ gateL,
    const int* __restrict__ counts,
    const int* __restrict__ tileE,
    const int* __restrict__ tileM0,
    float* __restrict__ out,
    int seg, int ldh, int nk) {
    __shared__ __align__(16) char lds[5][32768];
    int L = xcd_swz(blockIdx.x, gridDim.x);
    int mt = L / 3, ntl = L - mt * 3;
    int e = tileE[mt];
    if (e < 0) return;
    int m0 = tileM0[mt];
    int nrow = min(256, counts[e] - m0);
    const int* tok = tokL + e * T_TOK + m0;
    const float* gat = gateL + e * T_TOK + m0;
    int n0 = ntl * 256;

    const int tid = threadIdx.x, lane = tid & 63, wid = tid >> 6;
    const int wm = wid >> 2, wn = wid & 3;
    const int g = lane >> 4, r = lane & 15;

    int ar0 = wid * 16 + r;
    int ar1 = 128 + wid * 16 + r;
    const char* a0 = (const char*)h + ((size_t)(mt * 256 + ar0) * ldh) * 2 + g * 16;  // pad rows: row-isolated garbage
    const char* a1 = (const char*)h + ((size_t)(mt * 256 + ar1) * ldh) * 2 + g * 16;
    const char* bsl = (const char*)(dnt + (size_t)e * ID * HD) + (size_t)seg * ldh * 2;
    const char* b0 = bsl + (size_t)(n0 + wid * 16 + r) * (ID * 2) + g * 16;
    const char* b1 = bsl + (size_t)(n0 + 128 + wid * 16 + r) * (ID * 2) + g * 16;
    const int dst = wid * 1024;

    auto issue = [&](int step, int slot) {
        char* base = &lds[slot][0];
        int kb = step * 64;
        gload16(a0 + kb, base + dst);
        gload16(a1 + kb, base + 8192 + dst);
        gload16(b0 + kb, base + 16384 + dst);
        gload16(b1 + kb, base + 24576 + dst);
    };

    f32x4 acc[8][4];
#pragma unroll
    for (int m = 0; m < 8; m++)
#pragma unroll
        for (int n = 0; n < 4; n++) acc[m][n] = (f32x4){0.f, 0.f, 0.f, 0.f};

    issue(0, 0); issue(1, 1); issue(2, 2); issue(3, 3);
    asm volatile("s_waitcnt vmcnt(12)" ::: "memory");
    __builtin_amdgcn_s_barrier();
    asm volatile("" ::: "memory");

    const int aoff = wm * 8192 + g * 256 + r * 16;
    const int boff = 16384 + wn * 4096 + g * 256 + r * 16;

    for (int k = 0; k < nk; k++) {
        char* base = &lds[k % 5][0];
        bf16x8 a[4], b[4];
#pragma unroll
        for (int n = 0; n < 4; n++) b[n] = *(const bf16x8*)(base + boff + n * 1024);
#pragma unroll
        for (int m = 0; m < 4; m++) a[m] = *(const bf16x8*)(base + aoff + m * 1024);
        issue(min(k + 4, nk - 1), (k + 4) % 5);
        __builtin_amdgcn_s_setprio(1);
#pragma unroll
        for (int m = 0; m < 4; m++)
#pragma unroll
            for (int n = 0; n < 4; n++)
                acc[m][n] = __builtin_amdgcn_mfma_f32_16x16x32_bf16(a[m], b[n], acc[m][n], 0, 0, 0);
        __builtin_amdgcn_s_setprio(0);
#pragma unroll
        for (int m = 0; m < 4; m++) a[m] = *(const bf16x8*)(base + aoff + (4 + m) * 1024);
        __builtin_amdgcn_s_setprio(1);
#pragma unroll
        for (int m = 0; m < 4; m++)
#pragma unroll
            for (int n = 0; n < 4; n++)
                acc[4 + m][n] = __builtin_amdgcn_mfma_f32_16x16x32_bf16(a[m], b[n], acc[4 + m][n], 0, 0, 0);
        __builtin_amdgcn_s_setprio(0);
        asm volatile("s_waitcnt vmcnt(12)" ::: "memory");
        __builtin_amdgcn_s_barrier();
        asm volatile("" ::: "memory");
    }
    asm volatile("s_waitcnt vmcnt(0)" ::: "memory");

#pragma unroll
    for (int m = 0; m < 8; m++)
#pragma unroll
        for (int j = 0; j < 4; j++) {
            int rl = wm * 128 + m * 16 + g * 4 + j;
            if (rl < nrow) {
                int t = tok[rl];
                float gv = gat[rl];
                float* orow = out + (size_t)t * HD + n0 + wn * 64 + r;
#pragma unroll
                for (int n = 0; n < 4; n++)
                    atomicAdd(orow + n * 16, gv * acc[m][n][j]);
            }
        }
}

// ---------------- round-1 fused kernel (ws_size fallback) ----------------
__global__ __launch_bounds__(512, 2) void k_moe(
    const unsigned short* __restrict__ xb,
    const unsigned short* __restrict__ upt,
    const unsigned short* __restrict__ dnt,
    const int* __restrict__ counts,
    const int* __restrict__ tokL,
    const float* __restrict__ gateL,
    float* __restrict__ out) {
    __shared__ __align__(16) char lds[155648];
    char* xs = lds;
    char* hs = lds + 98304;
    char* ring = lds + 106496;

    const int e = blockIdx.x & 7;
    const int slot = blockIdx.x >> 3;
    const int cnt = counts[e];
    if (slot * 64 >= cnt) return;
    const int nrow = min(64, cnt - slot * 64);
    const int* tok = tokL + e * T_TOK + slot * 64;
    const float* gat = gateL + e * T_TOK + slot * 64;

    const int tid = threadIdx.x;
    const int lane = tid & 63;
    const int wid = tid >> 6;
    const int mi = wid >> 2, ni = wid & 3;

    const char* upe = (const char*)(upt + (size_t)e * ID * HD);
    const char* dne = (const char*)(dnt + (size_t)e * HD * ID);

    {
        int off = tid * 16;
#pragma unroll
        for (int s = 0; s < 12; s++) {
            int o = off + s * 8192;
            int m = o / 1536;
            int cb = o - m * 1536;
            int tk = (m < nrow) ? tok[m] : tok[0];
            const char* src = (const char*)xb + (size_t)tk * 1536 + (size_t)(cb ^ ((m & 7) << 4));
            gload16(src, xs + s * 8192 + wid * 1024);
        }
    }
    asm volatile("s_waitcnt vmcnt(0)" ::: "memory");
    __builtin_amdgcn_s_barrier();
    asm volatile("" ::: "memory");

    auto issue = [&](int s) {
        char* dstp = ring + (s % 6) * 8192 + wid * 1024;
        int ci = s / 24;
        int ph = s - ci * 24;
        int row = tid >> 3;
        int cb = (tid & 7) << 4;
        int scb = cb ^ ((row & 7) << 4);
        const char* src;
        if (ci >= 48) src = upe;
        else if (ph < 12) src = upe + (size_t)(ci * 64 + row) * 1536 + ph * 128 + scb;
        else              src = dne + (size_t)((ph - 12) * 64 + row) * 6144 + ci * 128 + scb;
        gload16(src, dstp);
    };

    f32x4 acc[2][12];
#pragma unroll
    for (int a = 0; a < 2; a++)
#pragma unroll
        for (int b = 0; b < 12; b++) acc[a][b] = (f32x4){0.f, 0.f, 0.f, 0.f};

    issue(0); issue(1); issue(2); issue(3);

    f32x4 acch[2];
    bf16x8 ha[2][2];

    for (int ci = 0; ci < 48; ci++) {
#pragma unroll
        for (int ks = 0; ks < 12; ks++) {
            issue(ci * 24 + ks + 4);
            asm volatile("s_waitcnt vmcnt(4)" ::: "memory");
            __builtin_amdgcn_s_barrier();
            asm volatile("" ::: "memory");
            char* buf = ring + (ks % 6) * 8192;
            if (ks == 0) { acch[0] = (f32x4){0.f,0.f,0.f,0.f}; acch[1] = (f32x4){0.f,0.f,0.f,0.f}; }
#pragma unroll
            for (int kkr = 0; kkr < 2; kkr++) {
                int bn = ni * 16 + (lane & 15);
                int bo = ((kkr * 32 + (lane >> 4) * 8) * 2) ^ ((bn & 7) << 4);
                bf16x8 bfrag = *(const bf16x8*)(buf + bn * 128 + bo);
#pragma unroll
                for (int mr = 0; mr < 2; mr++) {
                    int ar = mi * 32 + mr * 16 + (lane & 15);
                    int ao = ((ks * 64 + kkr * 32 + (lane >> 4) * 8) * 2) ^ ((ar & 7) << 4);
                    bf16x8 afrag = *(const bf16x8*)(xs + ar * 1536 + ao);
                    acch[mr] = __builtin_amdgcn_mfma_f32_16x16x32_bf16(afrag, bfrag, acch[mr], 0, 0, 0);
                }
            }
            if (ks == 11) {
#pragma unroll
                for (int mr = 0; mr < 2; mr++) {
                    int col = ni * 16 + (lane & 15);
#pragma unroll
                    for (int rr = 0; rr < 4; rr++) {
                        int m = mi * 32 + mr * 16 + (lane >> 4) * 4 + rr;
                        float v = acch[mr][rr];
                        *(unsigned short*)(hs + m * 128 + ((col * 2) ^ ((m & 7) << 4))) = f2bf(gelu_f(v));
                    }
                }
                asm volatile("s_waitcnt lgkmcnt(0)" ::: "memory");
            }
        }
#pragma unroll
        for (int j = 0; j < 12; j++) {
            issue(ci * 24 + 12 + j + 4);
            asm volatile("s_waitcnt vmcnt(4)" ::: "memory");
            __builtin_amdgcn_s_barrier();
            asm volatile("" ::: "memory");
            char* buf = ring + ((12 + j) % 6) * 8192;
            if (j == 0) {
#pragma unroll
                for (int mr = 0; mr < 2; mr++)
#pragma unroll
                    for (int kkr = 0; kkr < 2; kkr++) {
                        int ar = mi * 32 + mr * 16 + (lane & 15);
                        int ao = ((kkr * 32 + (lane >> 4) * 8) * 2) ^ ((ar & 7) << 4);
                        ha[mr][kkr] = *(const bf16x8*)(hs + ar * 128 + ao);
                    }
            }
#pragma unroll
            for (int kkr = 0; kkr < 2; kkr++) {
                int bn = ni * 16 + (lane & 15);
                int bo = ((kkr * 32 + (lane >> 4) * 8) * 2) ^ ((bn & 7) << 4);
                bf16x8 bfrag = *(const bf16x8*)(buf + bn * 128 + bo);
#pragma unroll
                for (int mr = 0; mr < 2; mr++)
                    acc[mr][j] = __builtin_amdgcn_mfma_f32_16x16x32_bf16(ha[mr][kkr], bfrag, acc[mr][j], 0, 0, 0);
            }
        }
    }

    int   t4[2][4];
    float g4[2][4];
#pragma unroll
    for (int mr = 0; mr < 2; mr++)
#pragma unroll
        for (int rr = 0; rr < 4; rr++) {
            int m = mi * 32 + mr * 16 + (lane >> 4) * 4 + rr;
            bool valid = m < nrow;
            t4[mr][rr] = valid ? tok[m] : -1;
            g4[mr][rr] = valid ? gat[m] : 0.f;
        }
#pragma unroll
    for (int mr = 0; mr < 2; mr++)
#pragma unroll
        for (int j = 0; j < 12; j++) {
            int colg = j * 64 + ni * 16 + (lane & 15);
#pragma unroll
            for (int rr = 0; rr < 4; rr++) {
                if (t4[mr][rr] >= 0)
                    atomicAdd(out + (size_t)t4[mr][rr] * HD + colg, g4[mr][rr] * acc[mr][j][rr]);
            }
        }
}

extern "C" void kernel_launch(void* const* d_in, const int* in_sizes, int n_in,
                              void* d_out, int out_size, void* d_ws, size_t ws_size,
                              hipStream_t stream) {
    const float* x  = (const float*)d_in[0];
    const float* rw = (const float*)d_in[1];
    const float* uw = (const float*)d_in[2];
    const float* dw = (const float*)d_in[3];
    float* out = (float*)d_out;

    size_t off = 0;
    char* base = (char*)d_ws;
    auto alloc = [&](size_t bytes) -> char* {
        char* p = base + off;
        off += (bytes + 1023) & ~(size_t)1023;
        return p;
    };
    unsigned short* xb   = (unsigned short*)alloc((size_t)T_TOK * HD * 2);
    unsigned short* upt  = (unsigned short*)alloc((size_t)NE * ID * HD * 2);
    unsigned short* dnt  = (unsigned short*)alloc((size_t)NE * HD * ID * 2);
    int*   topE   = (int*)alloc((size_t)T_TOK * 2 * 4);
    float* topW   = (float*)alloc((size_t)T_TOK * 2 * 4);
    int*   counts = (int*)alloc(256);
    int*   tileE  = (int*)alloc(NT1MAX * 4);
    int*   tileM0 = (int*)alloc(NT1MAX * 4);
    int*   tokL   = (int*)alloc((size_t)NE * T_TOK * 4);
    float* gateL  = (float*)alloc((size_t)NE * T_TOK * 4);
    size_t fixed = off;

    // pick smallest segment count S (dividing 12) whose h-buffer fits
    const int cand[6] = {1, 2, 3, 4, 6, 12};
    int S = 0;
    size_t hrows = (size_t)NT1MAX * 256;
    for (int i = 0; i < 6; i++) {
        size_t hb = hrows * (ID / cand[i]) * 2;
        if (fixed + hb <= ws_size) { S = cand[i]; break; }
    }
    unsigned short* h = (unsigned short*)(base + fixed);

    hipMemsetAsync(d_out, 0, (size_t)T_TOK * HD * 4, stream);
    hipMemsetAsync(counts, 0, 256, stream);

    k_tp<<<dim3(ID / 64, HD / 64, NE), 256, 0, stream>>>(uw, upt, HD, ID);   // -> [i][h]
    k_tp<<<dim3(HD / 64, ID / 64, NE), 256, 0, stream>>>(dw, dnt, ID, HD);   // -> [h][i]
    k_router<<<T_TOK / 4, 256, 0, stream>>>(x, rw, xb, topE, topW);
    k_scatter<<<T_TOK / 256, 256, 0, stream>>>(topE, topW, counts, tokL, gateL);

    if (S > 0) {
        int ldh = ID / S;          // h leading dim (elements)
        int ntn = ldh / 256;       // gemm1 n-tiles per segment
        int nk2 = ldh / 32;        // gemm2 k-steps per segment
        k_desc<<<1, 64, 0, stream>>>(counts, tileE, tileM0);
        for (int sg = 0; sg < S; sg++) {
            k_gemm1<<<NT1MAX * ntn, 512, 0, stream>>>(xb, upt, tokL, counts, tileE, tileM0,
                                                      h, sg, ntn, ldh);
            k_gemm2<<<NT1MAX * 3, 512, 0, stream>>>(h, dnt, tokL, gateL, counts, tileE, tileM0,
                                                    out, sg, ldh, nk2);
        }
    } else {
        k_moe<<<2048, 512, 0, stream>>>(xb, upt, dnt, counts, tokL, gateL, out);
    }
}

// Round 11
// 698.526 us; speedup vs baseline: 1.6830x; 1.0807x over previous
//
#include <hip/hip_runtime.h>

typedef short bf16x8 __attribute__((ext_vector_type(8)));
typedef float f32x4  __attribute__((ext_vector_type(4)));

#define T_TOK 16384
#define HD 768
#define ID 3072
#define NE 8
#define NT1MAX 136       // max 256-row tiles: 32768/256 + 8 partials

__device__ __forceinline__ unsigned short f2bf(float f) {
    unsigned int u = __float_as_uint(f);
    unsigned int r = (u + 0x7FFFu + ((u >> 16) & 1u)) >> 16;   // RNE
    return (unsigned short)r;
}

__device__ __forceinline__ void gload16(const void* g, void* l) {
    __builtin_amdgcn_global_load_lds(
        (const __attribute__((address_space(1))) void*)g,
        (__attribute__((address_space(3))) void*)l, 16, 0, 0);
}

__device__ __forceinline__ float gelu_f(float x) {
    // exact-GELU via A&S 7.1.26 erf approx (|err| <= 1.5e-7, invisible at bf16)
    float z = fabsf(x) * 0.70710678118f;
    float t = 1.0f / fmaf(0.3275911f, z, 1.0f);
    float p = t * fmaf(t, fmaf(t, fmaf(t, fmaf(t, 1.061405429f, -1.453152027f),
                                       1.421413741f), -0.284496736f), 0.254829592f);
    float e = 1.0f - p * __expf(-z * z);
    float erfv = (x >= 0.f) ? e : -e;
    return 0.5f * x * (1.0f + erfv);
}

__device__ __forceinline__ int xcd_swz(int bid, int nwg) {
    // bijective XCD-chunked remap (m204)
    int q = nwg >> 3, rr = nwg & 7;
    int xcd = bid & 7, seq = bid >> 3;
    return (xcd < rr ? xcd * (q + 1) : rr * (q + 1) + (xcd - rr) * q) + seq;
}

// ---- pack up_w [E][H][I] f32 -> upk: 16KB packet per (e,it,ks); unit (c,g,r) =
//      8 bf16 of up^T[i = it*256+c*16+r][h = ks*32+g*8 .. +8)
__global__ __launch_bounds__(256) void k_wpack_up(const float* __restrict__ uw,
                                                  unsigned short* __restrict__ upk) {
    int blk = blockIdx.x;                 // ((e*12 + it)*24 + ks)
    int ks = blk % 24, rem = blk / 24;
    int it = rem % 12, e = rem / 12;
    const float* src = uw + (size_t)e * HD * ID;
    char* dst = (char*)upk + (size_t)blk * 16384;
#pragma unroll
    for (int i4 = 0; i4 < 4; i4++) {
        int u = threadIdx.x + i4 * 256;
        int c = u >> 6, g = (u >> 4) & 3, r = u & 15;
        int icol = it * 256 + c * 16 + r;
        int h0 = ks * 32 + g * 8;
        unsigned short o[8];
#pragma unroll
        for (int b = 0; b < 8; b++) o[b] = f2bf(src[(size_t)(h0 + b) * ID + icol]);
        *(uint4*)(dst + (size_t)u * 16) = *(const uint4*)o;
    }
}

// ---- pack down_w [E][I][H] f32 -> dnk: 16KB packet per (e,nt,ks); unit (c,g,r) =
//      8 bf16 of down^T[h = nt*256+c*16+r][i = ks*32+g*8 .. +8)
__global__ __launch_bounds__(256) void k_wpack_dn(const float* __restrict__ dw,
                                                  unsigned short* __restrict__ dnk) {
    int blk = blockIdx.x;                 // ((e*3 + nt)*96 + ks)
    int ks = blk % 96, rem = blk / 96;
    int nt = rem % 3, e = rem / 3;
    const float* src = dw + (size_t)e * ID * HD;
    char* dst = (char*)dnk + (size_t)blk * 16384;
#pragma unroll
    for (int i4 = 0; i4 < 4; i4++) {
        int u = threadIdx.x + i4 * 256;
        int c = u >> 6, g = (u >> 4) & 3, r = u & 15;
        int hcol = nt * 256 + c * 16 + r;
        int i0 = ks * 32 + g * 8;
        unsigned short o[8];
#pragma unroll
        for (int b = 0; b < 8; b++) o[b] = f2bf(src[(size_t)(i0 + b) * HD + hcol]);
        *(uint4*)(dst + (size_t)u * 16) = *(const uint4*)o;
    }
}

// ---------------- router: wave per token, f32 ----------------
__global__ __launch_bounds__(256) void k_router(const float* __restrict__ x,
                                                const float* __restrict__ rw,
                                                int* __restrict__ topE,
                                                float* __restrict__ topW) {
    __shared__ float lrw[NE * HD];
    for (int i = threadIdx.x; i < NE * HD; i += 256) lrw[i] = rw[i];
    __syncthreads();
    int lane = threadIdx.x & 63;
    int t = blockIdx.x * 4 + (threadIdx.x >> 6);
    const float* xr = x + (size_t)t * HD;
    float acc[NE] = {0, 0, 0, 0, 0, 0, 0, 0};
    for (int h = lane; h < HD; h += 64) {
        float xv = xr[h];
#pragma unroll
        for (int e = 0; e < NE; e++) acc[e] = fmaf(xv, lrw[e * HD + h], acc[e]);
    }
#pragma unroll
    for (int e = 0; e < NE; e++) {
        float v = acc[e];
#pragma unroll
        for (int o = 32; o > 0; o >>= 1) v += __shfl_xor(v, o, 64);
        acc[e] = v;
    }
    if (lane == 0) {
        int e1 = 0; float l1 = acc[0];
#pragma unroll
        for (int e = 1; e < NE; e++) if (acc[e] > l1) { l1 = acc[e]; e1 = e; }
        int e2 = -1; float l2 = -1e30f;
#pragma unroll
        for (int e = 0; e < NE; e++) if (e != e1 && acc[e] > l2) { l2 = acc[e]; e2 = e; }
        float ex = expf(l2 - l1);
        float w1 = 1.0f / (1.0f + ex);
        topE[2 * t] = e1; topE[2 * t + 1] = e2;
        topW[2 * t] = w1; topW[2 * t + 1] = ex * w1;
    }
}

// ---------------- scatter into per-expert lists ----------------
__global__ __launch_bounds__(256) void k_scatter(const int* __restrict__ topE,
                                                 const float* __restrict__ topW,
                                                 int* __restrict__ counts,
                                                 int* __restrict__ tokL,
                                                 float* __restrict__ gateL) {
    __shared__ int lc[NE], lbase[NE];
    if (threadIdx.x < NE) lc[threadIdx.x] = 0;
    __syncthreads();
    int t = blockIdx.x * 256 + threadIdx.x;
    int e1 = topE[2 * t], e2 = topE[2 * t + 1];
    int p1 = atomicAdd(&lc[e1], 1);
    int p2 = atomicAdd(&lc[e2], 1);
    __syncthreads();
    if (threadIdx.x < NE) lbase[threadIdx.x] = atomicAdd(&counts[threadIdx.x], lc[threadIdx.x]);
    __syncthreads();
    int q1 = lbase[e1] + p1, q2 = lbase[e2] + p2;
    tokL[e1 * T_TOK + q1] = t;  gateL[e1 * T_TOK + q1] = topW[2 * t];
    tokL[e2 * T_TOK + q2] = t;  gateL[e2 * T_TOK + q2] = topW[2 * t + 1];
}

// ---------------- tile descriptor build: 256-row tiles ----------------
__global__ void k_desc(const int* __restrict__ counts, int* __restrict__ tileE,
                       int* __restrict__ tileM0) {
    if (threadIdx.x == 0 && blockIdx.x == 0) {
        int tl = 0;
        for (int e = 0; e < NE; e++) {
            int c = counts[e];
            int nt = (c + 255) >> 8;
            for (int t = 0; t < nt; t++) { tileE[tl] = e; tileM0[tl] = t << 8; tl++; }
        }
        for (; tl < NT1MAX; tl++) { tileE[tl] = -1; tileM0[tl] = 0; }
    }
}

// ---- gather + cvt + pack X: per (mt,ks) 16KB packet; unit (c,g,r) =
//      8 bf16 of x[tok[c*16+r]][h = ks*32+g*8 .. +8)
__global__ __launch_bounds__(256) void k_gpack(const float* __restrict__ x,
                                               const int* __restrict__ tokL,
                                               const int* __restrict__ counts,
                                               const int* __restrict__ tileE,
                                               const int* __restrict__ tileM0,
                                               unsigned short* __restrict__ xgk) {
    int blk = blockIdx.x;                 // mt*24 + ks
    int mt = blk / 24, ks = blk % 24;
    int e = tileE[mt];
    if (e < 0) return;
    int m0 = tileM0[mt];
    int nrow = min(256, counts[e] - m0);
    const int* tok = tokL + e * T_TOK + m0;
    char* dst = (char*)xgk + (size_t)blk * 16384;
#pragma unroll
    for (int i4 = 0; i4 < 4; i4++) {
        int u = threadIdx.x + i4 * 256;
        int c = u >> 6, g = (u >> 4) & 3, r = u & 15;
        int row = c * 16 + r;
        int tk = tok[row < nrow ? row : 0];
        const float* s = x + (size_t)tk * HD + ks * 32 + g * 8;
        unsigned short o[8];
#pragma unroll
        for (int b = 0; b < 8; b++) o[b] = f2bf(s[b]);
        *(uint4*)(dst + (size_t)u * 16) = *(const uint4*)o;
    }
}

// ============ grouped GEMM1: hk_seg = gelu( Xg @ up_seg^T ), all-linear staging =========
// 256x256 tile, BK=32, 5-slot ring (160KB), depth-3, vmcnt(12) per-wave BEFORE barrier
// (r7/r10 race discipline, tail dummies hit retired slot (k+4)%5=(k-1)%5).
// Every gload16 reads contiguous 1KB (packed operands); every ds_read_b128 contiguous-1KB.
__global__ __launch_bounds__(512, 1) void k_gemm1(
    const unsigned short* __restrict__ xgk,
    const unsigned short* __restrict__ upk,
    const int* __restrict__ counts,
    const int* __restrict__ tileE,
    const int* __restrict__ tileM0,
    unsigned short* __restrict__ hk,
    int seg, int ntn, int nk2) {
    __shared__ __align__(16) char lds[5][32768];
    constexpr int NK = HD / 32;                 // 24
    int L = xcd_swz(blockIdx.x, gridDim.x);
    int mt = L / ntn, ntl = L - mt * ntn;
    int e = tileE[mt];
    if (e < 0) return;
    int m0 = tileM0[mt];
    int nrow = min(256, counts[e] - m0);

    const int tid = threadIdx.x, lane = tid & 63, wid = tid >> 6;
    const int wm = wid >> 2, wn = wid & 3;
    const int g = lane >> 4, r = lane & 15;

    const char* abase = (const char*)xgk + (size_t)mt * (24 * 16384)
                        + (size_t)(2 * wid) * 1024 + (size_t)lane * 16;
    const char* bbase = (const char*)upk + (size_t)((e * 12 + seg * ntn + ntl) * 24) * 16384
                        + (size_t)(2 * wid) * 1024 + (size_t)lane * 16;
    const int dstoff = 2 * wid * 1024;          // wave-uniform; HW adds lane*16

    auto issue = [&](int step, int slot) {
        char* base = &lds[slot][0];
        const char* as = abase + (size_t)step * 16384;
        const char* bs = bbase + (size_t)step * 16384;
        gload16(as,        base + dstoff);
        gload16(as + 1024, base + dstoff + 1024);
        gload16(bs,        base + 16384 + dstoff);
        gload16(bs + 1024, base + 16384 + dstoff + 1024);
    };

    f32x4 acc[8][4];
#pragma unroll
    for (int m = 0; m < 8; m++)
#pragma unroll
        for (int n = 0; n < 4; n++) acc[m][n] = (f32x4){0.f, 0.f, 0.f, 0.f};

    issue(0, 0); issue(1, 1); issue(2, 2); issue(3, 3);
    asm volatile("s_waitcnt vmcnt(12)" ::: "memory");
    __builtin_amdgcn_s_barrier();
    asm volatile("" ::: "memory");

    const int aoff = wm * 8192 + g * 256 + r * 16;
    const int boff = 16384 + wn * 4096 + g * 256 + r * 16;

    for (int k = 0; k < NK; k++) {
        char* base = &lds[k % 5][0];
        bf16x8 a[4], b[4];
#pragma unroll
        for (int n = 0; n < 4; n++) b[n] = *(const bf16x8*)(base + boff + n * 1024);
#pragma unroll
        for (int m = 0; m < 4; m++) a[m] = *(const bf16x8*)(base + aoff + m * 1024);
        issue(min(k + 4, NK - 1), (k + 4) % 5);
        __builtin_amdgcn_s_setprio(1);
#pragma unroll
        for (int m = 0; m < 4; m++)
#pragma unroll
            for (int n = 0; n < 4; n++)
                acc[m][n] = __builtin_amdgcn_mfma_f32_16x16x32_bf16(a[m], b[n], acc[m][n], 0, 0, 0);
        __builtin_amdgcn_s_setprio(0);
#pragma unroll
        for (int m = 0; m < 4; m++) a[m] = *(const bf16x8*)(base + aoff + (4 + m) * 1024);
        __builtin_amdgcn_s_setprio(1);
#pragma unroll
        for (int m = 0; m < 4; m++)
#pragma unroll
            for (int n = 0; n < 4; n++)
                acc[4 + m][n] = __builtin_amdgcn_mfma_f32_16x16x32_bf16(a[m], b[n], acc[4 + m][n], 0, 0, 0);
        __builtin_amdgcn_s_setprio(0);
        asm volatile("s_waitcnt vmcnt(12)" ::: "memory");   // per-wave: tile k+1 landed
        __builtin_amdgcn_s_barrier();
        asm volatile("" ::: "memory");
    }
    asm volatile("s_waitcnt vmcnt(0)" ::: "memory");

    // epilogue: gelu -> hk in gemm2's packed layout [mt][ksl][c][g][r]
    char* hbase = (char*)hk + (size_t)mt * ((size_t)nk2 * 16384);
#pragma unroll
    for (int m = 0; m < 8; m++)
#pragma unroll
        for (int j = 0; j < 4; j++) {
            int rl = wm * 128 + m * 16 + g * 4 + j;
            if (rl < nrow) {
                int c = rl >> 4, rr = rl & 15;
#pragma unroll
                for (int n = 0; n < 4; n++) {
                    int col = ntl * 256 + wn * 64 + n * 16 + r;   // local i within segment
                    int ksl = col >> 5, gg = (col >> 3) & 3, b = col & 7;
                    *(unsigned short*)(hbase + (size_t)ksl * 16384 + c * 1024 + gg * 256 + rr * 16 + b * 2)
                        = f2bf(gelu_f(acc[m][n][j]));
                }
            }
        }
}

// ===== grouped GEMM2: out[tok] += gate * ( h_seg @ down_seg^T ), all-linear staging ====
__global__ __launch_bounds__(512, 1) void k_gemm2(
    const unsigned short* __restrict__ hk,
    const unsigned short* __restrict__ dnk,
    const int* __restrict__ tokL,
    const float* __restrict__ gateL,
    const int* __restrict__ counts,
    const int* __restrict__ tileE,
    const int* __restrict__ tileM0,
    float* __restrict__ out,
    int seg, int nk2) {
    __shared__ __align__(16) char lds[5][32768];
    int L = xcd_swz(blockIdx.x, gridDim.x);
    int mt = L / 3, ntl = L - mt * 3;
    int e = tileE[mt];
    if (e < 0) return;
    int m0 = tileM0[mt];
    int nrow = min(256, counts[e] - m0);
    const int* tok = tokL + e * T_TOK + m0;
    const float* gat = gateL + e * T_TOK + m0;
    int n0 = ntl * 256;

    const int tid = threadIdx.x, lane = tid & 63, wid = tid >> 6;
    const int wm = wid >> 2, wn = wid & 3;
    const int g = lane >> 4, r = lane & 15;

    const char* abase = (const char*)hk + (size_t)mt * ((size_t)nk2 * 16384)
                        + (size_t)(2 * wid) * 1024 + (size_t)lane * 16;
    const char* bbase = (const char*)dnk + (size_t)((e * 3 + ntl) * 96 + seg * nk2) * 16384
                        + (size_t)(2 * wid) * 1024 + (size_t)lane * 16;
    const int dstoff = 2 * wid * 1024;

    auto issue = [&](int step, int slot) {
        char* base = &lds[slot][0];
        const char* as = abase + (size_t)step * 16384;
        const char* bs = bbase + (size_t)step * 16384;
        gload16(as,        base + dstoff);
        gload16(as + 1024, base + dstoff + 1024);
        gload16(bs,        base + 16384 + dstoff);
        gload16(bs + 1024, base + 16384 + dstoff + 1024);
    };

    f32x4 acc[8][4];
#pragma unroll
    for (int m = 0; m < 8; m++)
#pragma unroll
        for (int n = 0; n < 4; n++) acc[m][n] = (f32x4){0.f, 0.f, 0.f, 0.f};

    issue(0, 0); issue(1, 1); issue(2, 2); issue(3, 3);
    asm volatile("s_waitcnt vmcnt(12)" ::: "memory");
    __builtin_amdgcn_s_barrier();
    asm volatile("" ::: "memory");

    const int aoff = wm * 8192 + g * 256 + r * 16;
    const int boff = 16384 + wn * 4096 + g * 256 + r * 16;

    for (int k = 0; k < nk2; k++) {
        char* base = &lds[k % 5][0];
        bf16x8 a[4], b[4];
#pragma unroll
        for (int n = 0; n < 4; n++) b[n] = *(const bf16x8*)(base + boff + n * 1024);
#pragma unroll
        for (int m = 0; m < 4; m++) a[m] = *(const bf16x8*)(base + aoff + m * 1024);
        issue(min(k + 4, nk2 - 1), (k + 4) % 5);
        __builtin_amdgcn_s_setprio(1);
#pragma unroll
        for (int m = 0; m < 4; m++)
#pragma unroll
            for (int n = 0; n < 4; n++)
                acc[m][n] = __builtin_amdgcn_mfma_f32_16x16x32_bf16(a[m], b[n], acc[m][n], 0, 0, 0);
        __builtin_amdgcn_s_setprio(0);
#pragma unroll
        for (int m = 0; m < 4; m++) a[m] = *(const bf16x8*)(base + aoff + (4 + m) * 1024);
        __builtin_amdgcn_s_setprio(1);
#pragma unroll
        for (int m = 0; m < 4; m++)
#pragma unroll
            for (int n = 0; n < 4; n++)
                acc[4 + m][n] = __builtin_amdgcn_mfma_f32_16x16x32_bf16(a[m], b[n], acc[4 + m][n], 0, 0, 0);
        __builtin_amdgcn_s_setprio(0);
        asm volatile("s_waitcnt vmcnt(12)" ::: "memory");
        __builtin_amdgcn_s_barrier();
        asm volatile("" ::: "memory");
    }
    asm volatile("s_waitcnt vmcnt(0)" ::: "memory");

#pragma unroll
    for (int m = 0; m < 8; m++)
#pragma unroll
        for (int j = 0; j < 4; j++) {
            int rl = wm * 128 + m * 16 + g * 4 + j;
            if (rl < nrow) {
                int t = tok[rl];
                float gv = gat[rl];
                float* orow = out + (size_t)t * HD + n0 + wn * 64 + r;
#pragma unroll
                for (int n = 0; n < 4; n++)
                    atomicAdd(orow + n * 16, gv * acc[m][n][j]);
            }
        }
}

extern "C" void kernel_launch(void* const* d_in, const int* in_sizes, int n_in,
                              void* d_out, int out_size, void* d_ws, size_t ws_size,
                              hipStream_t stream) {
    const float* x  = (const float*)d_in[0];
    const float* rw = (const float*)d_in[1];
    const float* uw = (const float*)d_in[2];
    const float* dw = (const float*)d_in[3];
    float* out = (float*)d_out;

    size_t off = 0;
    char* base = (char*)d_ws;
    auto alloc = [&](size_t bytes) -> char* {
        char* p = base + off;
        off += (bytes + 1023) & ~(size_t)1023;
        return p;
    };
    unsigned short* upk  = (unsigned short*)alloc((size_t)NE * ID * HD * 2);
    unsigned short* dnk  = (unsigned short*)alloc((size_t)NE * ID * HD * 2);
    int*   topE   = (int*)alloc((size_t)T_TOK * 2 * 4);
    float* topW   = (float*)alloc((size_t)T_TOK * 2 * 4);
    int*   counts = (int*)alloc(256);
    int*   tileE  = (int*)alloc(NT1MAX * 4);
    int*   tileM0 = (int*)alloc(NT1MAX * 4);
    int*   tokL   = (int*)alloc((size_t)NE * T_TOK * 4);
    float* gateL  = (float*)alloc((size_t)NE * T_TOK * 4);
    unsigned short* xgk = (unsigned short*)alloc((size_t)NT1MAX * 24 * 16384);
    size_t fixed = off;

    // smallest segment count S (dividing 12) whose h-buffer fits; floor S=12
    const int cand[6] = {1, 2, 3, 4, 6, 12};
    int S = 12;
    for (int i = 0; i < 6; i++) {
        size_t hb = (size_t)NT1MAX * 256 * (ID / cand[i]) * 2;
        if (fixed + hb <= ws_size) { S = cand[i]; break; }
    }
    unsigned short* hk = (unsigned short*)(base + fixed);

    hipMemsetAsync(d_out, 0, (size_t)T_TOK * HD * 4, stream);
    hipMemsetAsync(counts, 0, 256, stream);

    k_wpack_up<<<NE * 12 * 24, 256, 0, stream>>>(uw, upk);
    k_wpack_dn<<<NE * 3 * 96, 256, 0, stream>>>(dw, dnk);
    k_router<<<T_TOK / 4, 256, 0, stream>>>(x, rw, topE, topW);
    k_scatter<<<T_TOK / 256, 256, 0, stream>>>(topE, topW, counts, tokL, gateL);
    k_desc<<<1, 64, 0, stream>>>(counts, tileE, tileM0);
    k_gpack<<<NT1MAX * 24, 256, 0, stream>>>(x, tokL, counts, tileE, tileM0, xgk);

    int ldh = ID / S;
    int ntn = ldh / 256;
    int nk2 = ldh / 32;
    for (int sg = 0; sg < S; sg++) {
        k_gemm1<<<NT1MAX * ntn, 512, 0, stream>>>(xgk, upk, counts, tileE, tileM0,
                                                  hk, sg, ntn, nk2);
        k_gemm2<<<NT1MAX * 3, 512, 0, stream>>>(hk, dnk, tokL, gateL, counts, tileE, tileM0,
                                                out, sg, nk2);
    }
}